// Round 5
// baseline (471.937 us; speedup 1.0000x reference)
//
#include <hip/hip_runtime.h>

typedef __bf16 bf16x8 __attribute__((ext_vector_type(8)));
typedef float f32x4 __attribute__((ext_vector_type(4)));
typedef short s16x8 __attribute__((ext_vector_type(8)));

#define DEV __device__ __forceinline__

DEV float b2f(unsigned short u) {
  unsigned int x = ((unsigned int)u) << 16;
  return __builtin_bit_cast(float, x);
}
DEV unsigned short f2b(float f) {
  unsigned int x = __builtin_bit_cast(unsigned int, f);
  x += 0x7fffu + ((x >> 16) & 1u);
  return (unsigned short)(x >> 16);
}
DEV f32x4 mfma16(bf16x8 a, bf16x8 b, f32x4 c) {
  return __builtin_amdgcn_mfma_f32_16x16x32_bf16(a, b, c, 0, 0, 0);
}
DEV void gl2lds16(const unsigned short* g, unsigned short* l) {
  __builtin_amdgcn_global_load_lds(
      (const __attribute__((address_space(1))) void*)g,
      (__attribute__((address_space(3))) void*)l, 16, 0, 0);
}

// ------- tiled transpose + f32->bf16 convert: in[K][N] f32 (+z) -> out[N][K] bf16 -------
__global__ __launch_bounds__(256)
void transpose_k(const float* __restrict__ in, unsigned short* __restrict__ out,
                 int K, int N, long zin, long zout) {
  __shared__ float tile[32][33];
  in  += (size_t)blockIdx.z * zin;
  out += (size_t)blockIdx.z * zout;
  int n0 = blockIdx.x * 32, k0 = blockIdx.y * 32;
  int tx = threadIdx.x, ty = threadIdx.y;
  #pragma unroll
  for (int i = ty; i < 32; i += 8)
    tile[i][tx] = in[(size_t)(k0 + i) * N + n0 + tx];
  __syncthreads();
  #pragma unroll
  for (int i = ty; i < 32; i += 8)
    out[(size_t)(n0 + i) * K + k0 + tx] = f2b(tile[tx][i]);
}

// ------- V transpose: qkv v-cols [token][d] -> vT[bh][d][2048] (bf16->bf16) -------
__global__ __launch_bounds__(256)
void vtrans_k(const unsigned short* __restrict__ qkv, unsigned short* __restrict__ vT) {
  __shared__ unsigned short tile[32][33];
  int bh = blockIdx.z, b = bh >> 4, h = bh & 15;
  int t0 = blockIdx.x * 32, d0 = blockIdx.y * 32;
  const unsigned short* in = qkv + (size_t)b * 2048 * 3072 + 2048 + h * 64;
  unsigned short* out = vT + (size_t)bh * 64 * 2048;
  int tx = threadIdx.x, ty = threadIdx.y;
  #pragma unroll
  for (int i = ty; i < 32; i += 8)
    tile[i][tx] = in[(size_t)(t0 + i) * 3072 + d0 + tx];
  __syncthreads();
  #pragma unroll
  for (int i = ty; i < 32; i += 8)
    out[(size_t)(d0 + i) * 2048 + t0 + tx] = tile[tx][i];
}

// ---------------- LayerNorm over rows of 1024: f32 in -> bf16 out ----------------
__global__ __launch_bounds__(256)
void ln_kernel(const float* __restrict__ x, const float* __restrict__ g,
               const float* __restrict__ b, unsigned short* __restrict__ o) {
  __shared__ float rs[4];
  __shared__ float rq[4];
  int row = blockIdx.x, tid = threadIdx.x;
  const float* xr = x + (size_t)row * 1024;
  float4 raw = ((const float4*)xr)[tid];
  float s = raw.x + raw.y + raw.z + raw.w;
  float q = raw.x*raw.x + raw.y*raw.y + raw.z*raw.z + raw.w*raw.w;
  #pragma unroll
  for (int off = 32; off > 0; off >>= 1) {
    s += __shfl_down(s, off);
    q += __shfl_down(q, off);
  }
  int wave = tid >> 6;
  if ((tid & 63) == 0) { rs[wave] = s; rq[wave] = q; }
  __syncthreads();
  float ts = rs[0] + rs[1] + rs[2] + rs[3];
  float tq = rq[0] + rq[1] + rq[2] + rq[3];
  float mean = ts * (1.0f/1024.0f);
  float var = tq * (1.0f/1024.0f) - mean*mean;
  float rstd = rsqrtf(var + 1e-5f);
  float4 gr = ((const float4*)g)[tid];
  float4 br = ((const float4*)b)[tid];
  float o0 = (raw.x-mean)*rstd*gr.x + br.x;
  float o1 = (raw.y-mean)*rstd*gr.y + br.y;
  float o2 = (raw.z-mean)*rstd*gr.z + br.z;
  float o3 = (raw.w-mean)*rstd*gr.w + br.w;
  uint2 ov;
  ov.x = (unsigned int)f2b(o0) | ((unsigned int)f2b(o1) << 16);
  ov.y = (unsigned int)f2b(o2) | ((unsigned int)f2b(o3) << 16);
  ((uint2*)(o + (size_t)row * 1024))[tid] = ov;
}

// ------- out-init: out[r][c] = bias[c] + resid[r][c] (f32), N power of 2 -------
__global__ __launch_bounds__(256)
void initout_k(const float* __restrict__ bias, const float* __restrict__ resid,
               float* __restrict__ out, int N) {
  size_t i = (size_t)blockIdx.x * 256 + threadIdx.x;   // float4 index
  int c = (int)(i & ((N >> 2) - 1)) << 2;
  float4 r = ((const float4*)resid)[i];
  float4 b = *(const float4*)&bias[c];
  float4 o = {r.x + b.x, r.y + b.y, r.z + b.z, r.w + b.w};
  ((float4*)out)[i] = o;
}

// ------- GEMM: C[M][N] = A[M][K](bf16) * Bt[N][K](bf16)^T (+f32 bias/resid, relu) -------
template<bool RELU, bool BIAS, bool RESID, bool OUTF32>
__global__ __launch_bounds__(256)
void gemm_bt(const unsigned short* __restrict__ A, const unsigned short* __restrict__ Bt,
             const float* __restrict__ bias, const float* __restrict__ resid,
             void* __restrict__ Cv, int M, int N, int K) {
  __shared__ unsigned short As[128*32];
  __shared__ unsigned short Bs[128*32];
  const int tid = threadIdx.x;
  const int lane = tid & 63;
  const int quad = lane >> 4, l16 = lane & 15;
  const int wave = tid >> 6;
  const int m0 = blockIdx.y * 128, n0 = blockIdx.x * 128;
  const int wm = (wave >> 1) * 64, wn = (wave & 1) * 64;

  f32x4 acc[4][4];
  #pragma unroll
  for (int i = 0; i < 4; ++i)
    #pragma unroll
    for (int j = 0; j < 4; ++j) acc[i][j] = (f32x4){0.f, 0.f, 0.f, 0.f};

  const int srow = tid >> 2;
  const int scol = (tid & 3) * 8;
  const unsigned short* Ab = A + (size_t)m0 * K;
  const unsigned short* Bb = Bt + (size_t)n0 * K;

  for (int k0 = 0; k0 < K; k0 += 32) {
    gl2lds16(Ab + (size_t)srow * K + k0 + scol,        &As[tid * 8]);
    gl2lds16(Ab + (size_t)(srow + 64) * K + k0 + scol, &As[2048 + tid * 8]);
    gl2lds16(Bb + (size_t)srow * K + k0 + scol,        &Bs[tid * 8]);
    gl2lds16(Bb + (size_t)(srow + 64) * K + k0 + scol, &Bs[2048 + tid * 8]);
    __syncthreads();
    bf16x8 af[4], bfr[4];
    #pragma unroll
    for (int i = 0; i < 4; ++i)
      af[i] = __builtin_bit_cast(bf16x8, *(const s16x8*)&As[(wm + i*16 + l16)*32 + quad*8]);
    #pragma unroll
    for (int j = 0; j < 4; ++j)
      bfr[j] = __builtin_bit_cast(bf16x8, *(const s16x8*)&Bs[(wn + j*16 + l16)*32 + quad*8]);
    #pragma unroll
    for (int i = 0; i < 4; ++i)
      #pragma unroll
      for (int j = 0; j < 4; ++j)
        acc[i][j] = mfma16(af[i], bfr[j], acc[i][j]);
    __syncthreads();
  }

  #pragma unroll
  for (int i = 0; i < 4; ++i) {
    const int row = m0 + wm + i*16 + quad*4;
    #pragma unroll
    for (int j = 0; j < 4; ++j) {
      const int col = n0 + wn + j*16 + l16;
      float bv = 0.f;
      if (BIAS) bv = bias[col];
      #pragma unroll
      for (int r = 0; r < 4; ++r) {
        float v = acc[i][j][r] + bv;
        if (RESID) v += resid[(size_t)(row + r) * N + col];
        if (RELU) v = fmaxf(v, 0.f);
        if (OUTF32) ((float*)Cv)[(size_t)(row + r) * N + col] = v;
        else ((unsigned short*)Cv)[(size_t)(row + r) * N + col] = f2b(v);
      }
    }
  }
}

// ------- split-K GEMM: C[M][N](f32, pre-initialized) += A * Bt^T over K-chunk -------
// grid (N/128, M/128, S); chunk = K/S; epilogue atomicAdd f32.
__global__ __launch_bounds__(256)
void gemm_splitk(const unsigned short* __restrict__ A, const unsigned short* __restrict__ Bt,
                 float* __restrict__ C, int M, int N, int K, int KS) {
  __shared__ unsigned short As[128*32];
  __shared__ unsigned short Bs[128*32];
  const int tid = threadIdx.x;
  const int lane = tid & 63;
  const int quad = lane >> 4, l16 = lane & 15;
  const int wave = tid >> 6;
  const int m0 = blockIdx.y * 128, n0 = blockIdx.x * 128;
  const int wm = (wave >> 1) * 64, wn = (wave & 1) * 64;
  const int kbeg = blockIdx.z * KS, kend = kbeg + KS;

  f32x4 acc[4][4];
  #pragma unroll
  for (int i = 0; i < 4; ++i)
    #pragma unroll
    for (int j = 0; j < 4; ++j) acc[i][j] = (f32x4){0.f, 0.f, 0.f, 0.f};

  const int srow = tid >> 2;
  const int scol = (tid & 3) * 8;
  const unsigned short* Ab = A + (size_t)m0 * K;
  const unsigned short* Bb = Bt + (size_t)n0 * K;

  for (int k0 = kbeg; k0 < kend; k0 += 32) {
    gl2lds16(Ab + (size_t)srow * K + k0 + scol,        &As[tid * 8]);
    gl2lds16(Ab + (size_t)(srow + 64) * K + k0 + scol, &As[2048 + tid * 8]);
    gl2lds16(Bb + (size_t)srow * K + k0 + scol,        &Bs[tid * 8]);
    gl2lds16(Bb + (size_t)(srow + 64) * K + k0 + scol, &Bs[2048 + tid * 8]);
    __syncthreads();
    bf16x8 af[4], bfr[4];
    #pragma unroll
    for (int i = 0; i < 4; ++i)
      af[i] = __builtin_bit_cast(bf16x8, *(const s16x8*)&As[(wm + i*16 + l16)*32 + quad*8]);
    #pragma unroll
    for (int j = 0; j < 4; ++j)
      bfr[j] = __builtin_bit_cast(bf16x8, *(const s16x8*)&Bs[(wn + j*16 + l16)*32 + quad*8]);
    #pragma unroll
    for (int i = 0; i < 4; ++i)
      #pragma unroll
      for (int j = 0; j < 4; ++j)
        acc[i][j] = mfma16(af[i], bfr[j], acc[i][j]);
    __syncthreads();
  }

  #pragma unroll
  for (int i = 0; i < 4; ++i) {
    const int row = m0 + wm + i*16 + quad*4;
    #pragma unroll
    for (int j = 0; j < 4; ++j) {
      const int col = n0 + wn + j*16 + l16;
      #pragma unroll
      for (int r = 0; r < 4; ++r)
        atomicAdd(&C[(size_t)(row + r) * N + col], acc[i][j][r]);
    }
  }
}

// ---------------- causal flash attention, paired q-tiles + gl2lds double-buffer ------
__global__ __launch_bounds__(256)
void attn_kernel(const unsigned short* __restrict__ qkv,
                 const unsigned short* __restrict__ vT,
                 unsigned short* __restrict__ outc) {
  __shared__ unsigned short Ks[2][64*64];   // [kv][d], chunk-XOR swizzled
  __shared__ unsigned short Vs[2][64*64];   // [d][kv], chunk-XOR swizzled
  __shared__ unsigned short Ps[2][4*16*72]; // per-tile, per-wave P [16][72]
  const int tid = threadIdx.x, lane = tid & 63, wave = tid >> 6;
  const int quad = lane >> 4, l16 = lane & 15;
  const int bh = blockIdx.y, b = bh >> 4, h = bh & 15;
  const int jA = blockIdx.x, jB = 31 - jA;
  const size_t tokbase = (size_t)b * 2048 * 3072;
  const unsigned short* Q  = qkv + tokbase + h * 64;
  const unsigned short* Kg = qkv + tokbase + 1024 + h * 64;
  const unsigned short* Vg = vT + (size_t)bh * 64 * 2048;

  bf16x8 qf[2][2];
  #pragma unroll
  for (int t = 0; t < 2; ++t) {
    const int qrow = (t ? jB : jA) * 64 + wave * 16 + l16;
    #pragma unroll
    for (int s = 0; s < 2; ++s) {
      s16x8 raw = *(const s16x8*)(Q + (size_t)qrow * 3072 + s * 32 + quad * 8);
      unsigned short* rp = (unsigned short*)&raw;
      #pragma unroll
      for (int j = 0; j < 8; ++j) rp[j] = f2b(b2f(rp[j]) * 0.03125f);
      qf[t][s] = __builtin_bit_cast(bf16x8, raw);
    }
  }

  f32x4 accO[2][4];
  #pragma unroll
  for (int t = 0; t < 2; ++t)
    #pragma unroll
    for (int i = 0; i < 4; ++i) accO[t][i] = (f32x4){0.f, 0.f, 0.f, 0.f};
  float lrow[2][4] = {{0.f,0.f,0.f,0.f},{0.f,0.f,0.f,0.f}};

  const int r8 = lane >> 3;
  const int cs = (((lane & 7) ^ r8) * 8);

  auto stage = [&](int buf, int kv0) {
    #pragma unroll
    for (int i = 0; i < 2; ++i) {
      int row = wave * 16 + i * 8;
      gl2lds16(Kg + (size_t)(kv0 + row + r8) * 3072 + cs, &Ks[buf][row * 64 + lane * 8]);
      gl2lds16(Vg + (size_t)(row + r8) * 2048 + kv0 + cs, &Vs[buf][row * 64 + lane * 8]);
    }
  };

  const int ntile = jB + 1;
  stage(0, 0);
  __syncthreads();

  for (int it = 0; it < ntile; ++it) {
    const int buf = it & 1;
    if (it + 1 < ntile) stage(buf ^ 1, (it + 1) * 64);

    #pragma unroll
    for (int t = 0; t < 2; ++t) {
      const int jT = t ? jB : jA;
      if (it > jT) continue;
      f32x4 sv[4];
      #pragma unroll
      for (int ni = 0; ni < 4; ++ni) {
        sv[ni] = (f32x4){0.f, 0.f, 0.f, 0.f};
        #pragma unroll
        for (int s = 0; s < 2; ++s) {
          bf16x8 kf = __builtin_bit_cast(bf16x8,
            *(const s16x8*)&Ks[buf][(ni*16 + l16)*64 + (((s*4 + quad) ^ (l16 & 7)) * 8)]);
          sv[ni] = mfma16(qf[t][s], kf, sv[ni]);
        }
      }
      if (it == jT) {
        const int rowg = jT*64 + wave*16 + quad*4;
        const int kv0 = it * 64;
        #pragma unroll
        for (int ni = 0; ni < 4; ++ni) {
          const int colg = kv0 + ni*16 + l16;
          #pragma unroll
          for (int r = 0; r < 4; ++r)
            if (colg > rowg + r) sv[ni][r] = -__builtin_inff();
        }
      }
      float rsum[4] = {0.f, 0.f, 0.f, 0.f};
      unsigned short pb[4][4];
      #pragma unroll
      for (int ni = 0; ni < 4; ++ni)
        #pragma unroll
        for (int r = 0; r < 4; ++r) {
          float p = __expf(sv[ni][r]);
          rsum[r] += p;
          pb[ni][r] = f2b(p);
        }
      #pragma unroll
      for (int r = 0; r < 4; ++r) {
        float s2 = rsum[r];
        s2 += __shfl_xor(s2, 1);
        s2 += __shfl_xor(s2, 2);
        s2 += __shfl_xor(s2, 4);
        s2 += __shfl_xor(s2, 8);
        lrow[t][r] += s2;
      }
      #pragma unroll
      for (int ni = 0; ni < 4; ++ni)
        #pragma unroll
        for (int r = 0; r < 4; ++r)
          Ps[t][wave*1152 + (quad*4 + r)*72 + ni*16 + l16] = pb[ni][r];
      __asm__ volatile("s_waitcnt lgkmcnt(0)" ::: "memory");
      #pragma unroll
      for (int s = 0; s < 2; ++s) {
        bf16x8 pf = __builtin_bit_cast(bf16x8,
          *(const s16x8*)&Ps[t][wave*1152 + l16*72 + s*32 + quad*8]);
        #pragma unroll
        for (int ni = 0; ni < 4; ++ni) {
          bf16x8 vf = __builtin_bit_cast(bf16x8,
            *(const s16x8*)&Vs[buf][(ni*16 + l16)*64 + (((s*4 + quad) ^ (l16 & 7)) * 8)]);
          accO[t][ni] = mfma16(pf, vf, accO[t][ni]);
        }
      }
    }
    __syncthreads();
  }

  #pragma unroll
  for (int t = 0; t < 2; ++t) {
    const int rowg = (t ? jB : jA)*64 + wave*16 + quad*4;
    #pragma unroll
    for (int ni = 0; ni < 4; ++ni)
      #pragma unroll
      for (int r = 0; r < 4; ++r) {
        float o = accO[t][ni][r] / lrow[t][r];
        outc[(size_t)(b*2048 + rowg + r) * 1024 + h*64 + ni*16 + l16] = f2b(o);
      }
  }
}

extern "C" void kernel_launch(void* const* d_in, const int* in_sizes, int n_in,
                              void* d_out, int out_size, void* d_ws, size_t ws_size,
                              hipStream_t stream) {
  (void)in_sizes; (void)n_in; (void)out_size; (void)ws_size;
  const float* x   = (const float*)d_in[0];
  const float* wq  = (const float*)d_in[1];
  const float* wk  = (const float*)d_in[2];
  const float* wv  = (const float*)d_in[3];
  const float* wo  = (const float*)d_in[4];
  const float* bo  = (const float*)d_in[5];
  const float* g1  = (const float*)d_in[6];
  const float* b1  = (const float*)d_in[7];
  const float* g2  = (const float*)d_in[8];
  const float* b2  = (const float*)d_in[9];
  const float* w1  = (const float*)d_in[10];
  const float* bf1 = (const float*)d_in[11];
  const float* w2  = (const float*)d_in[12];
  const float* bf2 = (const float*)d_in[13];
  float* out = (float*)d_out;

  unsigned short* ws    = (unsigned short*)d_ws;
  unsigned short* wqkvt = ws;                        // bf16 [3072][1024]
  unsigned short* wot   = wqkvt + 3*1024*1024;       // bf16 [1024][1024]
  unsigned short* w1t   = wot   + 1024*1024;         // bf16 [4096][1024]
  unsigned short* w2t   = w1t   + 4096*1024;         // bf16 [1024][4096]
  unsigned short* hbuf  = w2t   + 4096*1024;         // bf16 [4096][1024] (LN1/LN2 out)
  unsigned short* qkvb  = hbuf  + 4096*1024;         // bf16 [4096][3072]
  unsigned short* attnb = qkvb  + (size_t)4096*3072; // bf16 [4096][1024]
  float*          x2b   = (float*)(attnb + 4096*1024); // f32 [4096][1024]
  unsigned short* vTb   = (unsigned short*)x2b;      // bf16 [32][64][2048] — dead before x2b written
  unsigned short* midb  = qkvb;                      // bf16 [4096][4096] overlaps qkvb+attnb (dead)

  dim3 tb(32, 8);
  transpose_k<<<dim3(2,32,16), tb, 0, stream>>>(wq, wqkvt,             1024, 64, 65536, 65536);
  transpose_k<<<dim3(2,32,16), tb, 0, stream>>>(wk, wqkvt + 1024*1024, 1024, 64, 65536, 65536);
  transpose_k<<<dim3(2,32,16), tb, 0, stream>>>(wv, wqkvt + 2048*1024, 1024, 64, 65536, 65536);
  transpose_k<<<dim3(32,32,1),  tb, 0, stream>>>(wo, wot, 1024, 1024, 0, 0);
  transpose_k<<<dim3(128,32,1), tb, 0, stream>>>(w1, w1t, 1024, 4096, 0, 0);
  transpose_k<<<dim3(32,128,1), tb, 0, stream>>>(w2, w2t, 4096, 1024, 0, 0);

  ln_kernel<<<4096, 256, 0, stream>>>(x, g1, b1, hbuf);
  gemm_bt<false,false,false,false><<<dim3(24,32), 256, 0, stream>>>(hbuf, wqkvt, nullptr, nullptr, qkvb, 4096, 3072, 1024);
  vtrans_k<<<dim3(64,2,32), tb, 0, stream>>>(qkvb, vTb);
  attn_kernel<<<dim3(16,32), 256, 0, stream>>>(qkvb, vTb, attnb);

  // out-proj: x2 = x + attn @ wo + bo   (split-K=4, atomic f32 accumulate)
  initout_k<<<4096, 256, 0, stream>>>(bo, x, x2b, 1024);
  gemm_splitk<<<dim3(8,32,4), 256, 0, stream>>>(attnb, wot, x2b, 4096, 1024, 1024, 256);

  ln_kernel<<<4096, 256, 0, stream>>>(x2b, g2, b2, hbuf);
  gemm_bt<true,true,false,false><<<dim3(32,32), 256, 0, stream>>>(hbuf, w1t, bf1, nullptr, midb, 4096, 4096, 1024);

  // FFN2: out = x2 + mid @ w2 + bf2   (split-K=4, atomic f32 accumulate)
  initout_k<<<4096, 256, 0, stream>>>(bf2, x2b, out, 1024);
  gemm_splitk<<<dim3(8,32,4), 256, 0, stream>>>(midb, w2t, out, 4096, 1024, 4096, 1024);
}

// Round 6
// 402.219 us; speedup vs baseline: 1.1733x; 1.1733x over previous
//
#include <hip/hip_runtime.h>

typedef __bf16 bf16x8 __attribute__((ext_vector_type(8)));
typedef float f32x4 __attribute__((ext_vector_type(4)));
typedef short s16x8 __attribute__((ext_vector_type(8)));

#define DEV __device__ __forceinline__

DEV float b2f(unsigned short u) {
  unsigned int x = ((unsigned int)u) << 16;
  return __builtin_bit_cast(float, x);
}
DEV unsigned short f2b(float f) {
  unsigned int x = __builtin_bit_cast(unsigned int, f);
  x += 0x7fffu + ((x >> 16) & 1u);
  return (unsigned short)(x >> 16);
}
DEV f32x4 mfma16(bf16x8 a, bf16x8 b, f32x4 c) {
  return __builtin_amdgcn_mfma_f32_16x16x32_bf16(a, b, c, 0, 0, 0);
}
DEV void gl2lds16(const unsigned short* g, unsigned short* l) {
  __builtin_amdgcn_global_load_lds(
      (const __attribute__((address_space(1))) void*)g,
      (__attribute__((address_space(3))) void*)l, 16, 0, 0);
}

// ------- tiled transpose + f32->bf16 convert: in[K][N] f32 (+z) -> out[N][K] bf16 -------
__global__ __launch_bounds__(256)
void transpose_k(const float* __restrict__ in, unsigned short* __restrict__ out,
                 int K, int N, long zin, long zout) {
  __shared__ float tile[32][33];
  in  += (size_t)blockIdx.z * zin;
  out += (size_t)blockIdx.z * zout;
  int n0 = blockIdx.x * 32, k0 = blockIdx.y * 32;
  int tx = threadIdx.x, ty = threadIdx.y;
  #pragma unroll
  for (int i = ty; i < 32; i += 8)
    tile[i][tx] = in[(size_t)(k0 + i) * N + n0 + tx];
  __syncthreads();
  #pragma unroll
  for (int i = ty; i < 32; i += 8)
    out[(size_t)(n0 + i) * K + k0 + tx] = f2b(tile[tx][i]);
}

// ------- V transpose: qkv v-cols [token][d] -> vT[bh][d][2048] (bf16->bf16) -------
__global__ __launch_bounds__(256)
void vtrans_k(const unsigned short* __restrict__ qkv, unsigned short* __restrict__ vT) {
  __shared__ unsigned short tile[32][33];
  int bh = blockIdx.z, b = bh >> 4, h = bh & 15;
  int t0 = blockIdx.x * 32, d0 = blockIdx.y * 32;
  const unsigned short* in = qkv + (size_t)b * 2048 * 3072 + 2048 + h * 64;
  unsigned short* out = vT + (size_t)bh * 64 * 2048;
  int tx = threadIdx.x, ty = threadIdx.y;
  #pragma unroll
  for (int i = ty; i < 32; i += 8)
    tile[i][tx] = in[(size_t)(t0 + i) * 3072 + d0 + tx];
  __syncthreads();
  #pragma unroll
  for (int i = ty; i < 32; i += 8)
    out[(size_t)(d0 + i) * 2048 + t0 + tx] = tile[tx][i];
}

// ---------------- LayerNorm over rows of 1024: f32 in -> bf16 out ----------------
__global__ __launch_bounds__(256)
void ln_kernel(const float* __restrict__ x, const float* __restrict__ g,
               const float* __restrict__ b, unsigned short* __restrict__ o) {
  __shared__ float rs[4];
  __shared__ float rq[4];
  int row = blockIdx.x, tid = threadIdx.x;
  const float* xr = x + (size_t)row * 1024;
  float4 raw = ((const float4*)xr)[tid];
  float s = raw.x + raw.y + raw.z + raw.w;
  float q = raw.x*raw.x + raw.y*raw.y + raw.z*raw.z + raw.w*raw.w;
  #pragma unroll
  for (int off = 32; off > 0; off >>= 1) {
    s += __shfl_down(s, off);
    q += __shfl_down(q, off);
  }
  int wave = tid >> 6;
  if ((tid & 63) == 0) { rs[wave] = s; rq[wave] = q; }
  __syncthreads();
  float ts = rs[0] + rs[1] + rs[2] + rs[3];
  float tq = rq[0] + rq[1] + rq[2] + rq[3];
  float mean = ts * (1.0f/1024.0f);
  float var = tq * (1.0f/1024.0f) - mean*mean;
  float rstd = rsqrtf(var + 1e-5f);
  float4 gr = ((const float4*)g)[tid];
  float4 br = ((const float4*)b)[tid];
  float o0 = (raw.x-mean)*rstd*gr.x + br.x;
  float o1 = (raw.y-mean)*rstd*gr.y + br.y;
  float o2 = (raw.z-mean)*rstd*gr.z + br.z;
  float o3 = (raw.w-mean)*rstd*gr.w + br.w;
  uint2 ov;
  ov.x = (unsigned int)f2b(o0) | ((unsigned int)f2b(o1) << 16);
  ov.y = (unsigned int)f2b(o2) | ((unsigned int)f2b(o3) << 16);
  ((uint2*)(o + (size_t)row * 1024))[tid] = ov;
}

// ------- GEMM: C[M][N] = A[M][K](bf16) * Bt[N][K](bf16)^T (+f32 bias/resid, relu) -------
// m97 structure + double-buffered LDS: stage tile k+1 while computing tile k, so the
// end-of-iter barrier vmcnt-drain overlaps compute (critical at 1 block/CU).
template<bool RELU, bool BIAS, bool RESID, bool OUTF32>
__global__ __launch_bounds__(256)
void gemm_bt(const unsigned short* __restrict__ A, const unsigned short* __restrict__ Bt,
             const float* __restrict__ bias, const float* __restrict__ resid,
             void* __restrict__ Cv, int M, int N, int K) {
  __shared__ unsigned short As[2][128*32];
  __shared__ unsigned short Bs[2][128*32];
  const int tid = threadIdx.x;
  const int lane = tid & 63;
  const int quad = lane >> 4, l16 = lane & 15;
  const int wave = tid >> 6;
  const int m0 = blockIdx.y * 128, n0 = blockIdx.x * 128;
  const int wm = (wave >> 1) * 64, wn = (wave & 1) * 64;

  f32x4 acc[4][4];
  #pragma unroll
  for (int i = 0; i < 4; ++i)
    #pragma unroll
    for (int j = 0; j < 4; ++j) acc[i][j] = (f32x4){0.f, 0.f, 0.f, 0.f};

  const int srow = tid >> 2;
  const int scol = (tid & 3) * 8;
  const unsigned short* Ab = A + (size_t)m0 * K;
  const unsigned short* Bb = Bt + (size_t)n0 * K;

  auto stage = [&](int buf, int k0) {
    gl2lds16(Ab + (size_t)srow * K + k0 + scol,        &As[buf][tid * 8]);
    gl2lds16(Ab + (size_t)(srow + 64) * K + k0 + scol, &As[buf][2048 + tid * 8]);
    gl2lds16(Bb + (size_t)srow * K + k0 + scol,        &Bs[buf][tid * 8]);
    gl2lds16(Bb + (size_t)(srow + 64) * K + k0 + scol, &Bs[buf][2048 + tid * 8]);
  };

  const int niter = K >> 5;
  stage(0, 0);
  __syncthreads();

  for (int it = 0; it < niter; ++it) {
    const int buf = it & 1;
    if (it + 1 < niter) stage(buf ^ 1, (it + 1) * 32);   // async, overlaps compute
    bf16x8 af[4], bfr[4];
    #pragma unroll
    for (int i = 0; i < 4; ++i)
      af[i] = __builtin_bit_cast(bf16x8, *(const s16x8*)&As[buf][(wm + i*16 + l16)*32 + quad*8]);
    #pragma unroll
    for (int j = 0; j < 4; ++j)
      bfr[j] = __builtin_bit_cast(bf16x8, *(const s16x8*)&Bs[buf][(wn + j*16 + l16)*32 + quad*8]);
    #pragma unroll
    for (int i = 0; i < 4; ++i)
      #pragma unroll
      for (int j = 0; j < 4; ++j)
        acc[i][j] = mfma16(af[i], bfr[j], acc[i][j]);
    __syncthreads();   // drains vmcnt -> next buf staged; also protects buf reuse
  }

  #pragma unroll
  for (int i = 0; i < 4; ++i) {
    const int row = m0 + wm + i*16 + quad*4;
    #pragma unroll
    for (int j = 0; j < 4; ++j) {
      const int col = n0 + wn + j*16 + l16;
      float bv = 0.f;
      if (BIAS) bv = bias[col];
      #pragma unroll
      for (int r = 0; r < 4; ++r) {
        float v = acc[i][j][r] + bv;
        if (RESID) v += resid[(size_t)(row + r) * N + col];
        if (RELU) v = fmaxf(v, 0.f);
        if (OUTF32) ((float*)Cv)[(size_t)(row + r) * N + col] = v;
        else ((unsigned short*)Cv)[(size_t)(row + r) * N + col] = f2b(v);
      }
    }
  }
}

// ---------------- causal flash attention, paired q-tiles + gl2lds double-buffer ------
__global__ __launch_bounds__(256)
void attn_kernel(const unsigned short* __restrict__ qkv,
                 const unsigned short* __restrict__ vT,
                 unsigned short* __restrict__ outc) {
  __shared__ unsigned short Ks[2][64*64];   // [kv][d], chunk-XOR swizzled
  __shared__ unsigned short Vs[2][64*64];   // [d][kv], chunk-XOR swizzled
  __shared__ unsigned short Ps[2][4*16*72]; // per-tile, per-wave P [16][72]
  const int tid = threadIdx.x, lane = tid & 63, wave = tid >> 6;
  const int quad = lane >> 4, l16 = lane & 15;
  const int bh = blockIdx.y, b = bh >> 4, h = bh & 15;
  const int jA = blockIdx.x, jB = 31 - jA;
  const size_t tokbase = (size_t)b * 2048 * 3072;
  const unsigned short* Q  = qkv + tokbase + h * 64;
  const unsigned short* Kg = qkv + tokbase + 1024 + h * 64;
  const unsigned short* Vg = vT + (size_t)bh * 64 * 2048;

  bf16x8 qf[2][2];
  #pragma unroll
  for (int t = 0; t < 2; ++t) {
    const int qrow = (t ? jB : jA) * 64 + wave * 16 + l16;
    #pragma unroll
    for (int s = 0; s < 2; ++s) {
      s16x8 raw = *(const s16x8*)(Q + (size_t)qrow * 3072 + s * 32 + quad * 8);
      unsigned short* rp = (unsigned short*)&raw;
      #pragma unroll
      for (int j = 0; j < 8; ++j) rp[j] = f2b(b2f(rp[j]) * 0.03125f);
      qf[t][s] = __builtin_bit_cast(bf16x8, raw);
    }
  }

  f32x4 accO[2][4];
  #pragma unroll
  for (int t = 0; t < 2; ++t)
    #pragma unroll
    for (int i = 0; i < 4; ++i) accO[t][i] = (f32x4){0.f, 0.f, 0.f, 0.f};
  float lrow[2][4] = {{0.f,0.f,0.f,0.f},{0.f,0.f,0.f,0.f}};

  const int r8 = lane >> 3;
  const int cs = (((lane & 7) ^ r8) * 8);

  auto stage = [&](int buf, int kv0) {
    #pragma unroll
    for (int i = 0; i < 2; ++i) {
      int row = wave * 16 + i * 8;
      gl2lds16(Kg + (size_t)(kv0 + row + r8) * 3072 + cs, &Ks[buf][row * 64 + lane * 8]);
      gl2lds16(Vg + (size_t)(row + r8) * 2048 + kv0 + cs, &Vs[buf][row * 64 + lane * 8]);
    }
  };

  const int ntile = jB + 1;
  stage(0, 0);
  __syncthreads();

  for (int it = 0; it < ntile; ++it) {
    const int buf = it & 1;
    if (it + 1 < ntile) stage(buf ^ 1, (it + 1) * 64);

    #pragma unroll
    for (int t = 0; t < 2; ++t) {
      const int jT = t ? jB : jA;
      if (it > jT) continue;
      f32x4 sv[4];
      #pragma unroll
      for (int ni = 0; ni < 4; ++ni) {
        sv[ni] = (f32x4){0.f, 0.f, 0.f, 0.f};
        #pragma unroll
        for (int s = 0; s < 2; ++s) {
          bf16x8 kf = __builtin_bit_cast(bf16x8,
            *(const s16x8*)&Ks[buf][(ni*16 + l16)*64 + (((s*4 + quad) ^ (l16 & 7)) * 8)]);
          sv[ni] = mfma16(qf[t][s], kf, sv[ni]);
        }
      }
      if (it == jT) {
        const int rowg = jT*64 + wave*16 + quad*4;
        const int kv0 = it * 64;
        #pragma unroll
        for (int ni = 0; ni < 4; ++ni) {
          const int colg = kv0 + ni*16 + l16;
          #pragma unroll
          for (int r = 0; r < 4; ++r)
            if (colg > rowg + r) sv[ni][r] = -__builtin_inff();
        }
      }
      float rsum[4] = {0.f, 0.f, 0.f, 0.f};
      unsigned short pb[4][4];
      #pragma unroll
      for (int ni = 0; ni < 4; ++ni)
        #pragma unroll
        for (int r = 0; r < 4; ++r) {
          float p = __expf(sv[ni][r]);
          rsum[r] += p;
          pb[ni][r] = f2b(p);
        }
      #pragma unroll
      for (int r = 0; r < 4; ++r) {
        float s2 = rsum[r];
        s2 += __shfl_xor(s2, 1);
        s2 += __shfl_xor(s2, 2);
        s2 += __shfl_xor(s2, 4);
        s2 += __shfl_xor(s2, 8);
        lrow[t][r] += s2;
      }
      #pragma unroll
      for (int ni = 0; ni < 4; ++ni)
        #pragma unroll
        for (int r = 0; r < 4; ++r)
          Ps[t][wave*1152 + (quad*4 + r)*72 + ni*16 + l16] = pb[ni][r];
      __asm__ volatile("s_waitcnt lgkmcnt(0)" ::: "memory");
      #pragma unroll
      for (int s = 0; s < 2; ++s) {
        bf16x8 pf = __builtin_bit_cast(bf16x8,
          *(const s16x8*)&Ps[t][wave*1152 + l16*72 + s*32 + quad*8]);
        #pragma unroll
        for (int ni = 0; ni < 4; ++ni) {
          bf16x8 vf = __builtin_bit_cast(bf16x8,
            *(const s16x8*)&Vs[buf][(ni*16 + l16)*64 + (((s*4 + quad) ^ (l16 & 7)) * 8)]);
          accO[t][ni] = mfma16(pf, vf, accO[t][ni]);
        }
      }
    }
    __syncthreads();
  }

  #pragma unroll
  for (int t = 0; t < 2; ++t) {
    const int rowg = (t ? jB : jA)*64 + wave*16 + quad*4;
    #pragma unroll
    for (int ni = 0; ni < 4; ++ni)
      #pragma unroll
      for (int r = 0; r < 4; ++r) {
        float o = accO[t][ni][r] / lrow[t][r];
        outc[(size_t)(b*2048 + rowg + r) * 1024 + h*64 + ni*16 + l16] = f2b(o);
      }
  }
}

extern "C" void kernel_launch(void* const* d_in, const int* in_sizes, int n_in,
                              void* d_out, int out_size, void* d_ws, size_t ws_size,
                              hipStream_t stream) {
  (void)in_sizes; (void)n_in; (void)out_size; (void)ws_size;
  const float* x   = (const float*)d_in[0];
  const float* wq  = (const float*)d_in[1];
  const float* wk  = (const float*)d_in[2];
  const float* wv  = (const float*)d_in[3];
  const float* wo  = (const float*)d_in[4];
  const float* bo  = (const float*)d_in[5];
  const float* g1  = (const float*)d_in[6];
  const float* b1  = (const float*)d_in[7];
  const float* g2  = (const float*)d_in[8];
  const float* b2  = (const float*)d_in[9];
  const float* w1  = (const float*)d_in[10];
  const float* bf1 = (const float*)d_in[11];
  const float* w2  = (const float*)d_in[12];
  const float* bf2 = (const float*)d_in[13];
  float* out = (float*)d_out;

  unsigned short* ws    = (unsigned short*)d_ws;
  unsigned short* wqkvt = ws;                        // bf16 [3072][1024]
  unsigned short* wot   = wqkvt + 3*1024*1024;       // bf16 [1024][1024]
  unsigned short* w1t   = wot   + 1024*1024;         // bf16 [4096][1024]
  unsigned short* w2t   = w1t   + 4096*1024;         // bf16 [1024][4096]
  unsigned short* hbuf  = w2t   + 4096*1024;         // bf16 [4096][1024] (LN1/LN2 out)
  unsigned short* qkvb  = hbuf  + 4096*1024;         // bf16 [4096][3072]
  unsigned short* attnb = qkvb  + (size_t)4096*3072; // bf16 [4096][1024]
  float*          x2b   = (float*)(attnb + 4096*1024); // f32 [4096][1024]
  unsigned short* vTb   = (unsigned short*)x2b;      // bf16 [32][64][2048] — dead before x2b written
  unsigned short* midb  = qkvb;                      // bf16 [4096][4096] overlaps qkvb+attnb (dead)

  dim3 tb(32, 8);
  transpose_k<<<dim3(2,32,16), tb, 0, stream>>>(wq, wqkvt,             1024, 64, 65536, 65536);
  transpose_k<<<dim3(2,32,16), tb, 0, stream>>>(wk, wqkvt + 1024*1024, 1024, 64, 65536, 65536);
  transpose_k<<<dim3(2,32,16), tb, 0, stream>>>(wv, wqkvt + 2048*1024, 1024, 64, 65536, 65536);
  transpose_k<<<dim3(32,32,1),  tb, 0, stream>>>(wo, wot, 1024, 1024, 0, 0);
  transpose_k<<<dim3(128,32,1), tb, 0, stream>>>(w1, w1t, 1024, 4096, 0, 0);
  transpose_k<<<dim3(32,128,1), tb, 0, stream>>>(w2, w2t, 4096, 1024, 0, 0);

  ln_kernel<<<4096, 256, 0, stream>>>(x, g1, b1, hbuf);
  gemm_bt<false,false,false,false><<<dim3(24,32), 256, 0, stream>>>(hbuf, wqkvt, nullptr, nullptr, qkvb, 4096, 3072, 1024);
  vtrans_k<<<dim3(64,2,32), tb, 0, stream>>>(qkvb, vTb);
  attn_kernel<<<dim3(16,32), 256, 0, stream>>>(qkvb, vTb, attnb);
  gemm_bt<false,true,true,true><<<dim3(8,32), 256, 0, stream>>>(attnb, wot, bo, x, x2b, 4096, 1024, 1024);
  ln_kernel<<<4096, 256, 0, stream>>>(x2b, g2, b2, hbuf);
  gemm_bt<true,true,false,false><<<dim3(32,32), 256, 0, stream>>>(hbuf, w1t, bf1, nullptr, midb, 4096, 4096, 1024);
  gemm_bt<false,true,true,true><<<dim3(8,32), 256, 0, stream>>>(midb, w2t, bf2, x2b, out, 4096, 1024, 4096);
}

// Round 7
// 380.592 us; speedup vs baseline: 1.2400x; 1.0568x over previous
//
#include <hip/hip_runtime.h>

typedef __bf16 bf16x8 __attribute__((ext_vector_type(8)));
typedef float f32x4 __attribute__((ext_vector_type(4)));
typedef short s16x8 __attribute__((ext_vector_type(8)));

#define DEV __device__ __forceinline__

DEV float b2f(unsigned short u) {
  unsigned int x = ((unsigned int)u) << 16;
  return __builtin_bit_cast(float, x);
}
DEV unsigned short f2b(float f) {
  unsigned int x = __builtin_bit_cast(unsigned int, f);
  x += 0x7fffu + ((x >> 16) & 1u);
  return (unsigned short)(x >> 16);
}
DEV f32x4 mfma16(bf16x8 a, bf16x8 b, f32x4 c) {
  return __builtin_amdgcn_mfma_f32_16x16x32_bf16(a, b, c, 0, 0, 0);
}
DEV void gl2lds16(const unsigned short* g, unsigned short* l) {
  __builtin_amdgcn_global_load_lds(
      (const __attribute__((address_space(1))) void*)g,
      (__attribute__((address_space(3))) void*)l, 16, 0, 0);
}

// ------- tiled transpose + f32->bf16 convert: in[K][N] f32 (+z) -> out[N][K] bf16 -------
__global__ __launch_bounds__(256)
void transpose_k(const float* __restrict__ in, unsigned short* __restrict__ out,
                 int K, int N, long zin, long zout) {
  __shared__ float tile[32][33];
  in  += (size_t)blockIdx.z * zin;
  out += (size_t)blockIdx.z * zout;
  int n0 = blockIdx.x * 32, k0 = blockIdx.y * 32;
  int tx = threadIdx.x, ty = threadIdx.y;
  #pragma unroll
  for (int i = ty; i < 32; i += 8)
    tile[i][tx] = in[(size_t)(k0 + i) * N + n0 + tx];
  __syncthreads();
  #pragma unroll
  for (int i = ty; i < 32; i += 8)
    out[(size_t)(n0 + i) * K + k0 + tx] = f2b(tile[tx][i]);
}

// ------- V transpose: qkv v-cols [token][d] -> vT[bh][d][2048] (bf16->bf16) -------
__global__ __launch_bounds__(256)
void vtrans_k(const unsigned short* __restrict__ qkv, unsigned short* __restrict__ vT) {
  __shared__ unsigned short tile[32][33];
  int bh = blockIdx.z, b = bh >> 4, h = bh & 15;
  int t0 = blockIdx.x * 32, d0 = blockIdx.y * 32;
  const unsigned short* in = qkv + (size_t)b * 2048 * 3072 + 2048 + h * 64;
  unsigned short* out = vT + (size_t)bh * 64 * 2048;
  int tx = threadIdx.x, ty = threadIdx.y;
  #pragma unroll
  for (int i = ty; i < 32; i += 8)
    tile[i][tx] = in[(size_t)(t0 + i) * 3072 + d0 + tx];
  __syncthreads();
  #pragma unroll
  for (int i = ty; i < 32; i += 8)
    out[(size_t)(d0 + i) * 2048 + t0 + tx] = tile[tx][i];
}

// ---------------- LayerNorm over rows of 1024: f32 in -> bf16 out ----------------
__global__ __launch_bounds__(256)
void ln_kernel(const float* __restrict__ x, const float* __restrict__ g,
               const float* __restrict__ b, unsigned short* __restrict__ o) {
  __shared__ float rs[4];
  __shared__ float rq[4];
  int row = blockIdx.x, tid = threadIdx.x;
  const float* xr = x + (size_t)row * 1024;
  float4 raw = ((const float4*)xr)[tid];
  float s = raw.x + raw.y + raw.z + raw.w;
  float q = raw.x*raw.x + raw.y*raw.y + raw.z*raw.z + raw.w*raw.w;
  #pragma unroll
  for (int off = 32; off > 0; off >>= 1) {
    s += __shfl_down(s, off);
    q += __shfl_down(q, off);
  }
  int wave = tid >> 6;
  if ((tid & 63) == 0) { rs[wave] = s; rq[wave] = q; }
  __syncthreads();
  float ts = rs[0] + rs[1] + rs[2] + rs[3];
  float tq = rq[0] + rq[1] + rq[2] + rq[3];
  float mean = ts * (1.0f/1024.0f);
  float var = tq * (1.0f/1024.0f) - mean*mean;
  float rstd = rsqrtf(var + 1e-5f);
  float4 gr = ((const float4*)g)[tid];
  float4 br = ((const float4*)b)[tid];
  float o0 = (raw.x-mean)*rstd*gr.x + br.x;
  float o1 = (raw.y-mean)*rstd*gr.y + br.y;
  float o2 = (raw.z-mean)*rstd*gr.z + br.z;
  float o3 = (raw.w-mean)*rstd*gr.w + br.w;
  uint2 ov;
  ov.x = (unsigned int)f2b(o0) | ((unsigned int)f2b(o1) << 16);
  ov.y = (unsigned int)f2b(o2) | ((unsigned int)f2b(o3) << 16);
  ((uint2*)(o + (size_t)row * 1024))[tid] = ov;
}

// ------- GEMM 128x128: C[M][N] = A * Bt^T (+f32 bias/resid, relu), dbuf LDS -------
template<bool RELU, bool BIAS, bool RESID, bool OUTF32>
__global__ __launch_bounds__(256)
void gemm_bt(const unsigned short* __restrict__ A, const unsigned short* __restrict__ Bt,
             const float* __restrict__ bias, const float* __restrict__ resid,
             void* __restrict__ Cv, int M, int N, int K) {
  __shared__ unsigned short As[2][128*32];
  __shared__ unsigned short Bs[2][128*32];
  const int tid = threadIdx.x;
  const int lane = tid & 63;
  const int quad = lane >> 4, l16 = lane & 15;
  const int wave = tid >> 6;
  const int m0 = blockIdx.y * 128, n0 = blockIdx.x * 128;
  const int wm = (wave >> 1) * 64, wn = (wave & 1) * 64;

  f32x4 acc[4][4];
  #pragma unroll
  for (int i = 0; i < 4; ++i)
    #pragma unroll
    for (int j = 0; j < 4; ++j) acc[i][j] = (f32x4){0.f, 0.f, 0.f, 0.f};

  const int srow = tid >> 2;
  const int scol = (tid & 3) * 8;
  const unsigned short* Ab = A + (size_t)m0 * K;
  const unsigned short* Bb = Bt + (size_t)n0 * K;

  auto stage = [&](int buf, int k0) {
    gl2lds16(Ab + (size_t)srow * K + k0 + scol,        &As[buf][tid * 8]);
    gl2lds16(Ab + (size_t)(srow + 64) * K + k0 + scol, &As[buf][2048 + tid * 8]);
    gl2lds16(Bb + (size_t)srow * K + k0 + scol,        &Bs[buf][tid * 8]);
    gl2lds16(Bb + (size_t)(srow + 64) * K + k0 + scol, &Bs[buf][2048 + tid * 8]);
  };

  const int niter = K >> 5;
  stage(0, 0);
  __syncthreads();

  for (int it = 0; it < niter; ++it) {
    const int buf = it & 1;
    if (it + 1 < niter) stage(buf ^ 1, (it + 1) * 32);
    bf16x8 af[4], bfr[4];
    #pragma unroll
    for (int i = 0; i < 4; ++i)
      af[i] = __builtin_bit_cast(bf16x8, *(const s16x8*)&As[buf][(wm + i*16 + l16)*32 + quad*8]);
    #pragma unroll
    for (int j = 0; j < 4; ++j)
      bfr[j] = __builtin_bit_cast(bf16x8, *(const s16x8*)&Bs[buf][(wn + j*16 + l16)*32 + quad*8]);
    #pragma unroll
    for (int i = 0; i < 4; ++i)
      #pragma unroll
      for (int j = 0; j < 4; ++j)
        acc[i][j] = mfma16(af[i], bfr[j], acc[i][j]);
    __syncthreads();
  }

  #pragma unroll
  for (int i = 0; i < 4; ++i) {
    const int row = m0 + wm + i*16 + quad*4;
    #pragma unroll
    for (int j = 0; j < 4; ++j) {
      const int col = n0 + wn + j*16 + l16;
      float bv = 0.f;
      if (BIAS) bv = bias[col];
      #pragma unroll
      for (int r = 0; r < 4; ++r) {
        float v = acc[i][j][r] + bv;
        if (RESID) v += resid[(size_t)(row + r) * N + col];
        if (RELU) v = fmaxf(v, 0.f);
        if (OUTF32) ((float*)Cv)[(size_t)(row + r) * N + col] = v;
        else ((unsigned short*)Cv)[(size_t)(row + r) * N + col] = f2b(v);
      }
    }
  }
}

// ------- GEMM 64x128 tile for N=1024 outputs: C(f32) = A*Bt^T + bias + resid -------
// grid: 1D, (M/64)*(N/128) blocks; 2 blocks/CU. XCD swizzle: id&7 = xcd, each xcd
// owns a contiguous 8-m-tile stripe so A-tile sharers hit the same L2.
__global__ __launch_bounds__(256)
void gemm_bt64(const unsigned short* __restrict__ A, const unsigned short* __restrict__ Bt,
               const float* __restrict__ bias, const float* __restrict__ resid,
               float* __restrict__ C, int M, int N, int K) {
  __shared__ unsigned short As[2][64*32];
  __shared__ unsigned short Bs[2][128*32];
  const int tid = threadIdx.x;
  const int lane = tid & 63;
  const int quad = lane >> 4, l16 = lane & 15;
  const int wave = tid >> 6;
  // swizzle: 512 blocks -> xcd stripe of m
  const int id = blockIdx.x;
  const int xcd = id & 7, i2 = id >> 3;
  const int mt = (xcd << 3) | (i2 >> 3);   // 0..63
  const int nt = i2 & 7;                   // 0..7
  const int m0 = mt * 64, n0 = nt * 128;
  const int wm = (wave >> 1) * 32, wn = (wave & 1) * 64;

  f32x4 acc[2][4];
  #pragma unroll
  for (int i = 0; i < 2; ++i)
    #pragma unroll
    for (int j = 0; j < 4; ++j) acc[i][j] = (f32x4){0.f, 0.f, 0.f, 0.f};

  const int srow = tid >> 2;
  const int scol = (tid & 3) * 8;
  const unsigned short* Ab = A + (size_t)m0 * K;
  const unsigned short* Bb = Bt + (size_t)n0 * K;

  auto stage = [&](int buf, int k0) {
    gl2lds16(Ab + (size_t)srow * K + k0 + scol,        &As[buf][tid * 8]);
    gl2lds16(Bb + (size_t)srow * K + k0 + scol,        &Bs[buf][tid * 8]);
    gl2lds16(Bb + (size_t)(srow + 64) * K + k0 + scol, &Bs[buf][2048 + tid * 8]);
  };

  const int niter = K >> 5;
  stage(0, 0);
  __syncthreads();

  for (int it = 0; it < niter; ++it) {
    const int buf = it & 1;
    if (it + 1 < niter) stage(buf ^ 1, (it + 1) * 32);
    bf16x8 af[2], bfr[4];
    #pragma unroll
    for (int i = 0; i < 2; ++i)
      af[i] = __builtin_bit_cast(bf16x8, *(const s16x8*)&As[buf][(wm + i*16 + l16)*32 + quad*8]);
    #pragma unroll
    for (int j = 0; j < 4; ++j)
      bfr[j] = __builtin_bit_cast(bf16x8, *(const s16x8*)&Bs[buf][(wn + j*16 + l16)*32 + quad*8]);
    #pragma unroll
    for (int i = 0; i < 2; ++i)
      #pragma unroll
      for (int j = 0; j < 4; ++j)
        acc[i][j] = mfma16(af[i], bfr[j], acc[i][j]);
    __syncthreads();
  }

  #pragma unroll
  for (int i = 0; i < 2; ++i) {
    const int row = m0 + wm + i*16 + quad*4;
    #pragma unroll
    for (int j = 0; j < 4; ++j) {
      const int col = n0 + wn + j*16 + l16;
      const float bv = bias[col];
      #pragma unroll
      for (int r = 0; r < 4; ++r) {
        float v = acc[i][j][r] + bv + resid[(size_t)(row + r) * N + col];
        C[(size_t)(row + r) * N + col] = v;
      }
    }
  }
}

// ---------------- causal flash attention, paired q-tiles + gl2lds double-buffer ------
__global__ __launch_bounds__(256)
void attn_kernel(const unsigned short* __restrict__ qkv,
                 const unsigned short* __restrict__ vT,
                 unsigned short* __restrict__ outc) {
  __shared__ unsigned short Ks[2][64*64];   // [kv][d], chunk-XOR swizzled
  __shared__ unsigned short Vs[2][64*64];   // [d][kv], chunk-XOR swizzled
  __shared__ unsigned short Ps[2][4*16*72]; // per-tile, per-wave P [16][72]
  const int tid = threadIdx.x, lane = tid & 63, wave = tid >> 6;
  const int quad = lane >> 4, l16 = lane & 15;
  const int bh = blockIdx.y, b = bh >> 4, h = bh & 15;
  const int jA = blockIdx.x, jB = 31 - jA;
  const size_t tokbase = (size_t)b * 2048 * 3072;
  const unsigned short* Q  = qkv + tokbase + h * 64;
  const unsigned short* Kg = qkv + tokbase + 1024 + h * 64;
  const unsigned short* Vg = vT + (size_t)bh * 64 * 2048;

  bf16x8 qf[2][2];
  #pragma unroll
  for (int t = 0; t < 2; ++t) {
    const int qrow = (t ? jB : jA) * 64 + wave * 16 + l16;
    #pragma unroll
    for (int s = 0; s < 2; ++s) {
      s16x8 raw = *(const s16x8*)(Q + (size_t)qrow * 3072 + s * 32 + quad * 8);
      unsigned short* rp = (unsigned short*)&raw;
      #pragma unroll
      for (int j = 0; j < 8; ++j) rp[j] = f2b(b2f(rp[j]) * 0.03125f);
      qf[t][s] = __builtin_bit_cast(bf16x8, raw);
    }
  }

  f32x4 accO[2][4];
  #pragma unroll
  for (int t = 0; t < 2; ++t)
    #pragma unroll
    for (int i = 0; i < 4; ++i) accO[t][i] = (f32x4){0.f, 0.f, 0.f, 0.f};
  float lrow[2][4] = {{0.f,0.f,0.f,0.f},{0.f,0.f,0.f,0.f}};

  const int r8 = lane >> 3;
  const int cs = (((lane & 7) ^ r8) * 8);

  auto stage = [&](int buf, int kv0) {
    #pragma unroll
    for (int i = 0; i < 2; ++i) {
      int row = wave * 16 + i * 8;
      gl2lds16(Kg + (size_t)(kv0 + row + r8) * 3072 + cs, &Ks[buf][row * 64 + lane * 8]);
      gl2lds16(Vg + (size_t)(row + r8) * 2048 + kv0 + cs, &Vs[buf][row * 64 + lane * 8]);
    }
  };

  const int ntile = jB + 1;
  stage(0, 0);
  __syncthreads();

  for (int it = 0; it < ntile; ++it) {
    const int buf = it & 1;
    if (it + 1 < ntile) stage(buf ^ 1, (it + 1) * 64);

    #pragma unroll
    for (int t = 0; t < 2; ++t) {
      const int jT = t ? jB : jA;
      if (it > jT) continue;
      f32x4 sv[4];
      #pragma unroll
      for (int ni = 0; ni < 4; ++ni) {
        sv[ni] = (f32x4){0.f, 0.f, 0.f, 0.f};
        #pragma unroll
        for (int s = 0; s < 2; ++s) {
          bf16x8 kf = __builtin_bit_cast(bf16x8,
            *(const s16x8*)&Ks[buf][(ni*16 + l16)*64 + (((s*4 + quad) ^ (l16 & 7)) * 8)]);
          sv[ni] = mfma16(qf[t][s], kf, sv[ni]);
        }
      }
      if (it == jT) {
        const int rowg = jT*64 + wave*16 + quad*4;
        const int kv0 = it * 64;
        #pragma unroll
        for (int ni = 0; ni < 4; ++ni) {
          const int colg = kv0 + ni*16 + l16;
          #pragma unroll
          for (int r = 0; r < 4; ++r)
            if (colg > rowg + r) sv[ni][r] = -__builtin_inff();
        }
      }
      float rsum[4] = {0.f, 0.f, 0.f, 0.f};
      unsigned short pb[4][4];
      #pragma unroll
      for (int ni = 0; ni < 4; ++ni)
        #pragma unroll
        for (int r = 0; r < 4; ++r) {
          float p = __expf(sv[ni][r]);
          rsum[r] += p;
          pb[ni][r] = f2b(p);
        }
      #pragma unroll
      for (int r = 0; r < 4; ++r) {
        float s2 = rsum[r];
        s2 += __shfl_xor(s2, 1);
        s2 += __shfl_xor(s2, 2);
        s2 += __shfl_xor(s2, 4);
        s2 += __shfl_xor(s2, 8);
        lrow[t][r] += s2;
      }
      #pragma unroll
      for (int ni = 0; ni < 4; ++ni)
        #pragma unroll
        for (int r = 0; r < 4; ++r)
          Ps[t][wave*1152 + (quad*4 + r)*72 + ni*16 + l16] = pb[ni][r];
      __asm__ volatile("s_waitcnt lgkmcnt(0)" ::: "memory");
      #pragma unroll
      for (int s = 0; s < 2; ++s) {
        bf16x8 pf = __builtin_bit_cast(bf16x8,
          *(const s16x8*)&Ps[t][wave*1152 + l16*72 + s*32 + quad*8]);
        #pragma unroll
        for (int ni = 0; ni < 4; ++ni) {
          bf16x8 vf = __builtin_bit_cast(bf16x8,
            *(const s16x8*)&Vs[buf][(ni*16 + l16)*64 + (((s*4 + quad) ^ (l16 & 7)) * 8)]);
          accO[t][ni] = mfma16(pf, vf, accO[t][ni]);
        }
      }
    }
    __syncthreads();
  }

  #pragma unroll
  for (int t = 0; t < 2; ++t) {
    const int rowg = (t ? jB : jA)*64 + wave*16 + quad*4;
    #pragma unroll
    for (int ni = 0; ni < 4; ++ni)
      #pragma unroll
      for (int r = 0; r < 4; ++r) {
        float o = accO[t][ni][r] / lrow[t][r];
        outc[(size_t)(b*2048 + rowg + r) * 1024 + h*64 + ni*16 + l16] = f2b(o);
      }
  }
}

extern "C" void kernel_launch(void* const* d_in, const int* in_sizes, int n_in,
                              void* d_out, int out_size, void* d_ws, size_t ws_size,
                              hipStream_t stream) {
  (void)in_sizes; (void)n_in; (void)out_size; (void)ws_size;
  const float* x   = (const float*)d_in[0];
  const float* wq  = (const float*)d_in[1];
  const float* wk  = (const float*)d_in[2];
  const float* wv  = (const float*)d_in[3];
  const float* wo  = (const float*)d_in[4];
  const float* bo  = (const float*)d_in[5];
  const float* g1  = (const float*)d_in[6];
  const float* b1  = (const float*)d_in[7];
  const float* g2  = (const float*)d_in[8];
  const float* b2  = (const float*)d_in[9];
  const float* w1  = (const float*)d_in[10];
  const float* bf1 = (const float*)d_in[11];
  const float* w2  = (const float*)d_in[12];
  const float* bf2 = (const float*)d_in[13];
  float* out = (float*)d_out;

  unsigned short* ws    = (unsigned short*)d_ws;
  unsigned short* wqkvt = ws;                        // bf16 [3072][1024]
  unsigned short* wot   = wqkvt + 3*1024*1024;       // bf16 [1024][1024]
  unsigned short* w1t   = wot   + 1024*1024;         // bf16 [4096][1024]
  unsigned short* w2t   = w1t   + 4096*1024;         // bf16 [1024][4096]
  unsigned short* hbuf  = w2t   + 4096*1024;         // bf16 [4096][1024] (LN1/LN2 out)
  unsigned short* qkvb  = hbuf  + 4096*1024;         // bf16 [4096][3072]
  unsigned short* attnb = qkvb  + (size_t)4096*3072; // bf16 [4096][1024]
  float*          x2b   = (float*)(attnb + 4096*1024); // f32 [4096][1024]
  unsigned short* vTb   = (unsigned short*)x2b;      // bf16 [32][64][2048] — dead before x2b written
  unsigned short* midb  = qkvb;                      // bf16 [4096][4096] overlaps qkvb+attnb (dead)

  dim3 tb(32, 8);
  transpose_k<<<dim3(2,32,16), tb, 0, stream>>>(wq, wqkvt,             1024, 64, 65536, 65536);
  transpose_k<<<dim3(2,32,16), tb, 0, stream>>>(wk, wqkvt + 1024*1024, 1024, 64, 65536, 65536);
  transpose_k<<<dim3(2,32,16), tb, 0, stream>>>(wv, wqkvt + 2048*1024, 1024, 64, 65536, 65536);
  transpose_k<<<dim3(32,32,1),  tb, 0, stream>>>(wo, wot, 1024, 1024, 0, 0);
  transpose_k<<<dim3(128,32,1), tb, 0, stream>>>(w1, w1t, 1024, 4096, 0, 0);
  transpose_k<<<dim3(32,128,1), tb, 0, stream>>>(w2, w2t, 4096, 1024, 0, 0);

  ln_kernel<<<4096, 256, 0, stream>>>(x, g1, b1, hbuf);
  gemm_bt<false,false,false,false><<<dim3(24,32), 256, 0, stream>>>(hbuf, wqkvt, nullptr, nullptr, qkvb, 4096, 3072, 1024);
  vtrans_k<<<dim3(64,2,32), tb, 0, stream>>>(qkvb, vTb);
  attn_kernel<<<dim3(16,32), 256, 0, stream>>>(qkvb, vTb, attnb);
  gemm_bt64<<<512, 256, 0, stream>>>(attnb, wot, bo, x, x2b, 4096, 1024, 1024);
  ln_kernel<<<4096, 256, 0, stream>>>(x2b, g2, b2, hbuf);
  gemm_bt<true,true,false,false><<<dim3(32,32), 256, 0, stream>>>(hbuf, w1t, bf1, nullptr, midb, 4096, 4096, 1024);
  gemm_bt64<<<512, 256, 0, stream>>>(midb, w2t, bf2, x2b, out, 4096, 1024, 4096);
}